// Round 2
// baseline (2261.095 us; speedup 1.0000x reference)
//
#include <hip/hip_runtime.h>
#include <cstdint>

#define B_DIM 32
#define T_DIM 1024
#define NIN 128
#define NHID 1024
#define KSLOT 8
#define NWORDS 36   // 2 guard words (64 zero bits) + 32 data words + 2 pad (16B-aligned columns)
#define TT 128      // t-tile held in LDS
#define NTILES (T_DIM / TT)

// ---------------- prep: pack spike input into per-(b,i) bit columns ----------------
// xbits[b][i][w]: bit (t&31) of word (2 + t/32) = (x[b][t][i] != 0)
__global__ void pack_bits_kernel(const float* __restrict__ x, uint32_t* __restrict__ xbits) {
    int b  = blockIdx.x >> 3;   // 32
    int wg = blockIdx.x & 7;    // 8 groups of 4 words
    int i  = threadIdx.x;       // 128
    const float* xp = x + (size_t)b * T_DIM * NIN + i;
    uint32_t* colp = xbits + ((size_t)b * NIN + i) * NWORDS;
    if (wg == 0) { colp[0] = 0u; colp[1] = 0u; }
    if (wg == 7) { colp[34] = 0u; colp[35] = 0u; }   // ws is poisoned 0xAA: keep pads clean
    for (int w = wg * 4; w < wg * 4 + 4; ++w) {
        uint32_t word = 0;
        #pragma unroll 4
        for (int bit = 0; bit < 32; ++bit) {
            float xv = xp[(size_t)(w * 32 + bit) * NIN];   // lanes = consecutive i -> coalesced
            word |= (xv != 0.0f) ? (1u << bit) : 0u;
        }
        colp[2 + w] = word;
    }
}

// ---------------- prep: pack (W, delay) into one u32, transposed to [i][h] ----------------
// d = round(sigmoid(draw)*50) in low 6 bits; W f32 with low 6 mantissa bits zeroed in the rest.
// (2^-18 relative truncation of W: irrelevant at the ~14-sigma spike margin.)
__global__ void pack_wd_kernel(const float* __restrict__ W, const float* __restrict__ draw,
                               uint32_t* __restrict__ WdT) {
    int idx = blockIdx.x * blockDim.x + threadIdx.x;   // 131072 = h*128 + i
    int h = idx >> 7, i = idx & 127;
    float w  = W[idx];
    float dr = draw[idx];
    float sg = 1.0f / (1.0f + expf(-dr));
    int d = (int)rintf(sg * 50.0f);                    // RNE matches jnp.round
    uint32_t wd = (__float_as_uint(w) & 0xffffffc0u) | (uint32_t)d;
    WdT[(size_t)i * NHID + h] = wd;
}

// ---------------- prep: out[0..255] = b_ro (logits bias), out[256..1279] = 0 (totals) ----------------
__global__ void init_out_kernel(float* __restrict__ out, const float* __restrict__ b_ro) {
    int idx = blockIdx.x * blockDim.x + threadIdx.x;
    if (idx < B_DIM * KSLOT) out[idx] = b_ro[0];
    else if (idx < B_DIM * KSLOT + T_DIM) out[idx] = 0.0f;
}

// ---------------- fused event-driven scatter + LIF scan ----------------
// block = (b, hg of 64 h), 256 threads = 4 waves. grid = 32*16 = 512 (2 blocks/CU).
// Per t-tile: all waves scatter spikes (disjoint i-ranges) into I_tile via ds_add_f32,
// barrier, wave 0 advances the LIF recurrence 128 steps (state in its registers), barrier.
__global__ __launch_bounds__(256, 2) void fused_kernel(
    const uint32_t* __restrict__ WdT, const uint32_t* __restrict__ xbits,
    float* __restrict__ out, const float* __restrict__ w_ro,
    const int* __restrict__ ss, const int* __restrict__ se) {
    __shared__ uint32_t lds_wd[NIN * 64];   // [i][hl] 32 KB
    __shared__ float    I_tile[TT * 64];    // [t][hl]  32 KB
    int bx = blockIdx.x;
    int hg = bx & 15;
    int b  = bx >> 4;
    int tid  = threadIdx.x;
    int lane = tid & 63;
    int sub  = tid >> 6;
    int hbase = hg * 64;

    for (int idx = tid; idx < NIN * 64; idx += 256)
        lds_wd[idx] = WdT[(size_t)(idx >> 6) * NHID + hbase + (idx & 63)];
    for (int idx = tid; idx < TT * 64; idx += 256)
        I_tile[idx] = 0.0f;

    // wave 0 carries the LIF state; it scatters fewer i's (20 vs 36) to balance.
    int ibeg = (sub == 0) ? 0 : 20 + (sub - 1) * 36;
    int iend = 20 + sub * 36;
    float v = 0.0f, rf = 0.0f;
    float sacc[KSLOT];
    int st[KSLOT], en[KSLOT];
    #pragma unroll
    for (int k = 0; k < KSLOT; ++k) { sacc[k] = 0.0f; st[k] = ss[k]; en[k] = se[k]; }

    const uint32_t* xcol = xbits + (size_t)b * NIN * NWORDS;
    __syncthreads();

    for (int tile = 0; tile < NTILES; ++tile) {
        int t0 = tile * TT;
        // ---- scatter: sources ts in [t0-51, t0+126] live in words 4*tile .. 4*tile+5 ----
        for (int i = ibeg; i < iend; ++i) {
            uint32_t wd = lds_wd[(i << 6) | lane];
            int   d  = (int)(wd & 63u);
            float wf = __int_as_float((int)(wd & 0xffffffc0u));
            const uint32_t* xc = xcol + (size_t)i * NWORDS + tile * 4;  // 16B-aligned
            uint4 w4 = *(const uint4*)xc;        // words 4t..4t+3
            uint2 w2 = *(const uint2*)(xc + 4);  // words 4t+4, 4t+5
            uint32_t wv[6] = {w4.x, w4.y, w4.z, w4.w, w2.x, w2.y};
            #pragma unroll
            for (int w = 0; w < 6; ++w) {
                uint32_t word = (uint32_t)__builtin_amdgcn_readfirstlane((int)wv[w]);
                // tt = ts+1+d-t0 = (32*(4*tile+w)+j-64)+1+d-t0 = 32*w-63 + j + d
                int base = 32 * w - 63;
                while (word) {
                    int j = __ffs(word) - 1;
                    word &= word - 1;
                    int tt = base + j + d;       // per-lane via d
                    if ((unsigned)tt < (unsigned)TT)
                        atomicAdd(&I_tile[(tt << 6) | lane], wf);   // bank = lane%32: conflict-free
                }
            }
        }
        __syncthreads();
        // ---- LIF: wave 0 only, sequential in t; reads then re-zeros the tile ----
        if (sub == 0) {
            for (int u = 0; u < TT; u += 4) {
                float Iv[4];
                #pragma unroll
                for (int c = 0; c < 4; ++c) Iv[c] = I_tile[((u + c) << 6) | lane];
                #pragma unroll
                for (int c = 0; c < 4; ++c) I_tile[((u + c) << 6) | lane] = 0.0f;
                #pragma unroll
                for (int c = 0; c < 4; ++c) {
                    int t = t0 + u + c;
                    bool active = (rf <= 0.0f);
                    float vupd = v + 0.1f * (Iv[c] - v);   // v + alpha*(-v + I)
                    float vn = active ? vupd : v;
                    bool spike = active && (vn >= 1.0f);
                    unsigned long long bal = __ballot(spike);
                    if (bal != 0ULL) {                      // rare path (~14 sigma)
                        if (spike) {
                            vn = 0.0f;                      // V_RESET
                            #pragma unroll
                            for (int k = 0; k < KSLOT; ++k)
                                if (t >= st[k] && t < en[k]) sacc[k] += 1.0f;
                        }
                        rf = spike ? 2.0f : fmaxf(rf - 1.0f, 0.0f);
                        if (lane == 0) atomicAdd(&out[B_DIM * KSLOT + t], (float)__popcll(bal));
                    } else {
                        rf = fmaxf(rf - 1.0f, 0.0f);
                    }
                    v = vn;
                }
            }
        }
        __syncthreads();
    }
    // ---- epilogue: logits[b][k] += sum_h sacc[k] * w_ro[h] ----
    if (sub == 0) {
        float wr = w_ro[hbase + lane];
        #pragma unroll
        for (int k = 0; k < KSLOT; ++k) {
            float val = sacc[k] * wr;
            #pragma unroll
            for (int o = 32; o > 0; o >>= 1) val += __shfl_down(val, o);
            if (lane == 0) atomicAdd(&out[b * KSLOT + k], val);
        }
    }
}

extern "C" void kernel_launch(void* const* d_in, const int* in_sizes, int n_in,
                              void* d_out, int out_size, void* d_ws, size_t ws_size,
                              hipStream_t stream) {
    const float* x   = (const float*)d_in[0];
    const float* W   = (const float*)d_in[1];
    const float* drw = (const float*)d_in[2];
    const float* wro = (const float*)d_in[3];
    const float* bro = (const float*)d_in[4];
    const int*   ss  = (const int*)d_in[5];
    const int*   se  = (const int*)d_in[6];
    float* out = (float*)d_out;

    uintptr_t base = (uintptr_t)d_ws;
    size_t off = 0;
    auto take = [&](size_t bytes) {
        size_t o = off;
        off = (off + bytes + 255) & ~(size_t)255;
        return (void*)(base + o);
    };
    uint32_t* xbits = (uint32_t*)take((size_t)B_DIM * NIN * NWORDS * 4);
    uint32_t* WdT   = (uint32_t*)take((size_t)NIN * NHID * 4);
    (void)ws_size;

    pack_bits_kernel<<<256, 128, 0, stream>>>(x, xbits);
    pack_wd_kernel<<<512, 256, 0, stream>>>(W, drw, WdT);
    init_out_kernel<<<5, 256, 0, stream>>>(out, bro);
    fused_kernel<<<512, 256, 0, stream>>>(WdT, xbits, out, wro, ss, se);
}

// Round 3
// 2259.323 us; speedup vs baseline: 1.0008x; 1.0008x over previous
//
#include <hip/hip_runtime.h>
#include <cstdint>

#define B_DIM 32
#define T_DIM 1024
#define NIN 128
#define NHID 1024
#define KSLOT 8
#define NWORDS 36   // 2 guard words (64 zero bits) + 32 data words + 2 pad (16B-aligned columns)
#define TT 128      // t-tile held in LDS
#define NTILES (T_DIM / TT)

// Raw LDS float atomic add: ds_add_f32 (no return). Avoids clang's CAS-loop
// expansion of fp atomicAdd under IEEE-denormal mode (round-2 lesson: that CAS
// loop cost ~300 dependent LDS cycles per visit -> 2.2 ms). Low 32 bits of a
// generic pointer to LDS are the LDS byte offset (shared aperture is 4GB-aligned).
__device__ __forceinline__ void lds_fadd(float* p, float v) {
    uint32_t off = (uint32_t)(uintptr_t)p;
    asm volatile("ds_add_f32 %0, %1" :: "v"(off), "v"(v) : "memory");
}

// ---------------- prep: pack spike input into per-(b,i) bit columns ----------------
// xbits[b][i][w]: bit (t&31) of word (2 + t/32) = (x[b][t][i] != 0)
__global__ void pack_bits_kernel(const float* __restrict__ x, uint32_t* __restrict__ xbits) {
    int b  = blockIdx.x >> 3;   // 32
    int wg = blockIdx.x & 7;    // 8 groups of 4 words
    int i  = threadIdx.x;       // 128
    const float* xp = x + (size_t)b * T_DIM * NIN + i;
    uint32_t* colp = xbits + ((size_t)b * NIN + i) * NWORDS;
    if (wg == 0) { colp[0] = 0u; colp[1] = 0u; }
    if (wg == 7) { colp[34] = 0u; colp[35] = 0u; }   // ws is poisoned 0xAA: keep pads clean
    for (int w = wg * 4; w < wg * 4 + 4; ++w) {
        uint32_t word = 0;
        #pragma unroll 4
        for (int bit = 0; bit < 32; ++bit) {
            float xv = xp[(size_t)(w * 32 + bit) * NIN];   // lanes = consecutive i -> coalesced
            word |= (xv != 0.0f) ? (1u << bit) : 0u;
        }
        colp[2 + w] = word;
    }
}

// ---------------- prep: pack (W, delay) into one u32, transposed to [i][h] ----------------
__global__ void pack_wd_kernel(const float* __restrict__ W, const float* __restrict__ draw,
                               uint32_t* __restrict__ WdT) {
    int idx = blockIdx.x * blockDim.x + threadIdx.x;   // 131072 = h*128 + i
    int h = idx >> 7, i = idx & 127;
    float w  = W[idx];
    float dr = draw[idx];
    float sg = 1.0f / (1.0f + expf(-dr));
    int d = (int)rintf(sg * 50.0f);                    // RNE matches jnp.round
    uint32_t wd = (__float_as_uint(w) & 0xffffffc0u) | (uint32_t)d;
    WdT[(size_t)i * NHID + h] = wd;
}

// ---------------- prep: out[0..255] = b_ro (logits bias), out[256..1279] = 0 (totals) ----------------
__global__ void init_out_kernel(float* __restrict__ out, const float* __restrict__ b_ro) {
    int idx = blockIdx.x * blockDim.x + threadIdx.x;
    if (idx < B_DIM * KSLOT) out[idx] = b_ro[0];
    else if (idx < B_DIM * KSLOT + T_DIM) out[idx] = 0.0f;
}

// ---------------- fused event-driven scatter + LIF scan ----------------
// block = (b, hg of 64 h), 256 threads = 4 waves. grid = 32*16 = 512 (2 blocks/CU).
// Per t-tile: all waves scatter spikes (disjoint i-ranges) into I_tile via ds_add_f32,
// barrier, wave 0 advances the LIF recurrence 128 steps (state in its registers), barrier.
__global__ __launch_bounds__(256, 2) void fused_kernel(
    const uint32_t* __restrict__ WdT, const uint32_t* __restrict__ xbits,
    float* __restrict__ out, const float* __restrict__ w_ro,
    const int* __restrict__ ss, const int* __restrict__ se) {
    __shared__ uint32_t lds_wd[NIN * 64];   // [i][hl] 32 KB
    __shared__ float    I_tile[TT * 64];    // [t][hl]  32 KB
    int bx = blockIdx.x;
    int hg = bx & 15;
    int b  = bx >> 4;
    int tid  = threadIdx.x;
    int lane = tid & 63;
    int sub  = tid >> 6;
    int hbase = hg * 64;

    for (int idx = tid; idx < NIN * 64; idx += 256)
        lds_wd[idx] = WdT[(size_t)(idx >> 6) * NHID + hbase + (idx & 63)];
    for (int idx = tid; idx < TT * 64; idx += 256)
        I_tile[idx] = 0.0f;

    // wave 0 carries the LIF state; it scatters fewer i's (20 vs 36) to balance.
    int ibeg = (sub == 0) ? 0 : 20 + (sub - 1) * 36;
    int iend = 20 + sub * 36;
    float v = 0.0f, rf = 0.0f;
    float sacc[KSLOT];
    int st[KSLOT], en[KSLOT];
    #pragma unroll
    for (int k = 0; k < KSLOT; ++k) { sacc[k] = 0.0f; st[k] = ss[k]; en[k] = se[k]; }

    const uint32_t* xcol = xbits + (size_t)b * NIN * NWORDS;
    __syncthreads();

    for (int tile = 0; tile < NTILES; ++tile) {
        int t0 = tile * TT;
        // ---- scatter: sources ts in [t0-51, t0+126] live in words 4*tile .. 4*tile+5 ----
        for (int i = ibeg; i < iend; ++i) {
            uint32_t wd = lds_wd[(i << 6) | lane];
            int   d  = (int)(wd & 63u);
            float wf = __int_as_float((int)(wd & 0xffffffc0u));
            const uint32_t* xc = xcol + (size_t)i * NWORDS + tile * 4;  // 16B-aligned
            uint4 w4 = *(const uint4*)xc;        // words 4t..4t+3
            uint2 w2 = *(const uint2*)(xc + 4);  // words 4t+4, 4t+5
            uint32_t wv[6] = {w4.x, w4.y, w4.z, w4.w, w2.x, w2.y};
            // tt = ts+1+d-t0 = 32*w - 63 + j + d;  valid windows per w (j in [0,31], d in [0,50]):
            //   w=0: tt in [-63,18]  -> only j>=13 can ever land   (pre-mask)
            //   w=1: tt in [-31,50]  -> guarded
            //   w=2: tt in [  1,82]  -> always valid
            //   w=3: tt in [ 33,114] -> always valid
            //   w=4: tt in [ 65,146] -> guarded
            //   w=5: tt in [ 97,178] -> only j<=30 can ever land   (pre-mask)
            #pragma unroll
            for (int w = 0; w < 6; ++w) {
                uint32_t word = (uint32_t)__builtin_amdgcn_readfirstlane((int)wv[w]);
                if (w == 0) word &= 0xffffe000u;
                if (w == 5) word &= 0x7fffffffu;
                int base = 32 * w - 63;
                while (word) {
                    int j = __ffs(word) - 1;
                    word &= word - 1;
                    int tt = base + j + d;       // per-lane via d
                    if (w == 2 || w == 3) {
                        lds_fadd(&I_tile[(tt << 6) | lane], wf);           // always in-range
                    } else {
                        if ((unsigned)tt < (unsigned)TT)                   // exec-mask guard
                            lds_fadd(&I_tile[(tt << 6) | lane], wf);
                    }
                }
            }
        }
        __syncthreads();
        // ---- LIF: wave 0 only, sequential in t; reads then re-zeros the tile ----
        if (sub == 0) {
            for (int u = 0; u < TT; u += 4) {
                float Iv[4];
                #pragma unroll
                for (int c = 0; c < 4; ++c) Iv[c] = I_tile[((u + c) << 6) | lane];
                #pragma unroll
                for (int c = 0; c < 4; ++c) I_tile[((u + c) << 6) | lane] = 0.0f;
                #pragma unroll
                for (int c = 0; c < 4; ++c) {
                    int t = t0 + u + c;
                    bool active = (rf <= 0.0f);
                    float vupd = v + 0.1f * (Iv[c] - v);   // v + alpha*(-v + I)
                    float vn = active ? vupd : v;
                    bool spike = active && (vn >= 1.0f);
                    unsigned long long bal = __ballot(spike);
                    if (bal != 0ULL) {                      // rare path (~14 sigma)
                        if (spike) {
                            vn = 0.0f;                      // V_RESET
                            #pragma unroll
                            for (int k = 0; k < KSLOT; ++k)
                                if (t >= st[k] && t < en[k]) sacc[k] += 1.0f;
                        }
                        rf = spike ? 2.0f : fmaxf(rf - 1.0f, 0.0f);
                        if (lane == 0) atomicAdd(&out[B_DIM * KSLOT + t], (float)__popcll(bal));
                    } else {
                        rf = fmaxf(rf - 1.0f, 0.0f);
                    }
                    v = vn;
                }
            }
        }
        __syncthreads();
    }
    // ---- epilogue: logits[b][k] += sum_h sacc[k] * w_ro[h] ----
    if (sub == 0) {
        float wr = w_ro[hbase + lane];
        #pragma unroll
        for (int k = 0; k < KSLOT; ++k) {
            float val = sacc[k] * wr;
            #pragma unroll
            for (int o = 32; o > 0; o >>= 1) val += __shfl_down(val, o);
            if (lane == 0) atomicAdd(&out[b * KSLOT + k], val);
        }
    }
}

extern "C" void kernel_launch(void* const* d_in, const int* in_sizes, int n_in,
                              void* d_out, int out_size, void* d_ws, size_t ws_size,
                              hipStream_t stream) {
    const float* x   = (const float*)d_in[0];
    const float* W   = (const float*)d_in[1];
    const float* drw = (const float*)d_in[2];
    const float* wro = (const float*)d_in[3];
    const float* bro = (const float*)d_in[4];
    const int*   ss  = (const int*)d_in[5];
    const int*   se  = (const int*)d_in[6];
    float* out = (float*)d_out;

    uintptr_t base = (uintptr_t)d_ws;
    size_t off = 0;
    auto take = [&](size_t bytes) {
        size_t o = off;
        off = (off + bytes + 255) & ~(size_t)255;
        return (void*)(base + o);
    };
    uint32_t* xbits = (uint32_t*)take((size_t)B_DIM * NIN * NWORDS * 4);
    uint32_t* WdT   = (uint32_t*)take((size_t)NIN * NHID * 4);
    (void)ws_size;

    pack_bits_kernel<<<256, 128, 0, stream>>>(x, xbits);
    pack_wd_kernel<<<512, 256, 0, stream>>>(W, drw, WdT);
    init_out_kernel<<<5, 256, 0, stream>>>(out, bro);
    fused_kernel<<<512, 256, 0, stream>>>(WdT, xbits, out, wro, ss, se);
}

// Round 4
// 431.387 us; speedup vs baseline: 5.2415x; 5.2373x over previous
//
#include <hip/hip_runtime.h>
#include <cstdint>

#define B_DIM 32
#define T_DIM 1024
#define NIN 128
#define NHID 1024
#define KSLOT 8
#define NWORDS 34   // 2 guard words (64 zero bits) + 32 data words
#define WAVES 8     // waves per block
#define CHUNKS 32   // 32-t chunks over T=1024
#define ROUNDS (CHUNKS / WAVES)

typedef float f32x2 __attribute__((ext_vector_type(2)));

// ---------------- prep: pack spike input into per-(b,i) bit columns ----------------
// xbits[b][i][w]: bit (t&31) of word (2 + t/32) = (x[b][t][i] != 0)
__global__ void pack_bits_kernel(const float* __restrict__ x, uint32_t* __restrict__ xbits) {
    int b  = blockIdx.x >> 3;   // 32
    int wg = blockIdx.x & 7;    // 8 groups of 4 words
    int i  = threadIdx.x;       // 128
    const float* xp = x + (size_t)b * T_DIM * NIN + i;
    uint32_t* colp = xbits + ((size_t)b * NIN + i) * NWORDS;
    if (wg == 0) { colp[0] = 0u; colp[1] = 0u; }
    for (int w = wg * 4; w < wg * 4 + 4; ++w) {
        uint32_t word = 0;
        #pragma unroll 4
        for (int bit = 0; bit < 32; ++bit) {
            float xv = xp[(size_t)(w * 32 + bit) * NIN];   // lanes = consecutive i -> coalesced
            word |= (xv != 0.0f) ? (1u << bit) : 0u;
        }
        colp[2 + w] = word;
    }
}

// ---------------- prep: pack (W, delay) into one u32, transposed to [i][h] ----------------
// d = round(sigmoid(draw)*50) in low 6 bits; W f32 with low 6 mantissa bits zeroed in the rest.
// (identical to round-1 version: end-to-end verified, absmax == 0)
__global__ void pack_wd_kernel(const float* __restrict__ W, const float* __restrict__ draw,
                               uint32_t* __restrict__ WdT) {
    int idx = blockIdx.x * blockDim.x + threadIdx.x;   // 131072 = h*128 + i
    int h = idx >> 7, i = idx & 127;
    float w  = W[idx];
    float dr = draw[idx];
    float sg = 1.0f / (1.0f + expf(-dr));
    int d = (int)rintf(sg * 50.0f);                    // RNE matches jnp.round
    uint32_t wd = (__float_as_uint(w) & 0xffffffc0u) | (uint32_t)d;
    WdT[(size_t)i * NHID + h] = wd;
}

// ---------------- prep: out[0..255] = b_ro (logits bias), out[256..1279] = 0 (totals) ----------------
__global__ void init_out_kernel(float* __restrict__ out, const float* __restrict__ b_ro) {
    int idx = blockIdx.x * blockDim.x + threadIdx.x;
    if (idx < B_DIM * KSLOT) out[idx] = b_ro[0];
    else if (idx < B_DIM * KSLOT + T_DIM) out[idx] = 0.0f;
}

// ---------------- fused dense bit-ladder + wave-relay LIF ----------------
// block = (b, hg of 64 h), 512 threads = 8 waves. grid = 32*16 = 512 -> 2 blocks/CU,
// 16 waves/CU (4/SIMD). Wave sub computes I (acc[32] regs) for chunk c = 8r+sub via the
// round-1 bit-ladder, then relays LIF state (v, rf, sacc) wave->wave through LDS guarded
// by a flag counter. No I intermediate, no __syncthreads in the main loop.
__global__ __launch_bounds__(512, 4) void fused_kernel(
    const uint32_t* __restrict__ WdT, const uint32_t* __restrict__ xbits,
    float* __restrict__ out, const float* __restrict__ w_ro,
    const int* __restrict__ ss, const int* __restrict__ se) {
    __shared__ uint32_t lds_wd[NIN * 64];     // [i][hl] 32 KB
    __shared__ uint32_t lds_x[NIN * NWORDS];  // [i][w]  17 KB
    __shared__ float st_v[64];                // relay state: membrane
    __shared__ float st_rf[64];               // relay state: refractory
    __shared__ float st_sacc[KSLOT][64];      // relay state: slot spike acc
    __shared__ int   flag;                    // relay counter: next chunk allowed to run LIF

    int bx = blockIdx.x;
    int hg = bx & 15;
    int b  = bx >> 4;
    int tid  = threadIdx.x;
    int lane = tid & 63;
    int sub  = tid >> 6;
    int hbase = hg * 64;

    for (int idx = tid; idx < NIN * 64; idx += 512)
        lds_wd[idx] = WdT[(size_t)(idx >> 6) * NHID + hbase + (idx & 63)];
    for (int idx = tid; idx < NIN * NWORDS; idx += 512)
        lds_x[idx] = xbits[(size_t)b * NIN * NWORDS + idx];
    if (tid < 64) { st_v[tid] = 0.0f; st_rf[tid] = 0.0f; }
    ((float*)st_sacc)[tid] = 0.0f;            // KSLOT*64 == 512 == blockDim
    if (tid == 0) flag = 0;
    __syncthreads();

    // slot bounds -> SGPRs (wave-uniform)
    int st_[KSLOT], en_[KSLOT];
    #pragma unroll
    for (int k = 0; k < KSLOT; ++k) {
        st_[k] = __builtin_amdgcn_readfirstlane(ss[k]);
        en_[k] = __builtin_amdgcn_readfirstlane(se[k]);
    }
    float wr = w_ro[hbase + lane];

    float v = 0.0f, rf = 0.0f;
    float sacc[KSLOT];
    #pragma unroll
    for (int k = 0; k < KSLOT; ++k) sacc[k] = 0.0f;

    for (int r = 0; r < ROUNDS; ++r) {
        int c  = r * WAVES + sub;
        int t0 = c * 32;
        // ---- dense bit-ladder: acc[2j+s] = I[t0+2j+s] for this wave's 64 h ----
        f32x2 acc[16];
        #pragma unroll
        for (int j = 0; j < 16; ++j) acc[j] = (f32x2)0.0f;
        #pragma unroll 2
        for (int i = 0; i < NIN; ++i) {
            uint32_t wd = lds_wd[(i << 6) | lane];    // fixed i per wave -> broadcast-friendly
            int d     = (int)(wd & 63u);
            int wbits = (int)(wd & 0xffffffc0u);      // W with low 6 mantissa bits dropped
            int sp = t0 + 63 - d;                     // +64 guard bits; sp >= 13
            int q = sp >> 5, rr = sp & 31;
            uint32_t lo = lds_x[i * NWORDS + q];      // <=3 distinct addrs across the wave
            uint32_t hi = lds_x[i * NWORDS + q + 1];
            uint32_t mask = (uint32_t)(((((uint64_t)hi) << 32) | lo) >> rr);
            // bit k of mask == x[b, t0+k-1-d, i]   (verified exact in round 1)
            #pragma unroll
            for (int j = 0; j < 16; ++j) {
                int s0 = ((int)(mask << (31 - 2 * j))) >> 31;   // v_bfe_i32: 0 or -1
                int s1 = ((int)(mask << (30 - 2 * j))) >> 31;
                f32x2 add;
                add.x = __int_as_float(wbits & s0);
                add.y = __int_as_float(wbits & s1);
                acc[j] += add;                                   // v_pk_add_f32
            }
        }
        // ---- wait for relay token ----
        while (__builtin_amdgcn_readfirstlane(*(volatile int*)&flag) != c)
            __builtin_amdgcn_s_sleep(1);
        // ---- load state, run 32 LIF steps from acc registers ----
        v  = st_v[lane];
        rf = st_rf[lane];
        #pragma unroll
        for (int k = 0; k < KSLOT; ++k) sacc[k] = st_sacc[k][lane];
        #pragma unroll
        for (int k = 0; k < 32; ++k) {
            float I = (k & 1) ? acc[k >> 1].y : acc[k >> 1].x;
            int t = t0 + k;
            bool active = (rf <= 0.0f);
            float vupd = v + 0.1f * (I - v);          // v + alpha*(-v + I)
            float vn = active ? vupd : v;
            bool spike = active && (vn >= 1.0f);
            unsigned long long bal = __ballot(spike);
            if (bal != 0ULL) {                         // rare path (~no spikes at this margin)
                if (spike) {
                    vn = 0.0f;                         // V_RESET
                    #pragma unroll
                    for (int k2 = 0; k2 < KSLOT; ++k2)
                        if (t >= st_[k2] && t < en_[k2]) sacc[k2] += 1.0f;
                }
                rf = spike ? 2.0f : fmaxf(rf - 1.0f, 0.0f);
                if (lane == 0) atomicAdd(&out[B_DIM * KSLOT + t], (float)__popcll(bal));
            } else {
                rf = fmaxf(rf - 1.0f, 0.0f);
            }
            v = vn;
        }
        // ---- write back state, release token ----
        st_v[lane]  = v;
        st_rf[lane] = rf;
        #pragma unroll
        for (int k = 0; k < KSLOT; ++k) st_sacc[k][lane] = sacc[k];
        __threadfence_block();                         // drain LDS writes before flag
        if (lane == 0) *(volatile int*)&flag = c + 1;
    }
    // ---- epilogue: wave owning chunk 31 holds final sacc ----
    if (sub == WAVES - 1) {
        #pragma unroll
        for (int k = 0; k < KSLOT; ++k) {
            float val = sacc[k] * wr;
            #pragma unroll
            for (int o = 32; o > 0; o >>= 1) val += __shfl_down(val, o);
            if (lane == 0) atomicAdd(&out[b * KSLOT + k], val);
        }
    }
}

extern "C" void kernel_launch(void* const* d_in, const int* in_sizes, int n_in,
                              void* d_out, int out_size, void* d_ws, size_t ws_size,
                              hipStream_t stream) {
    const float* x   = (const float*)d_in[0];
    const float* W   = (const float*)d_in[1];
    const float* drw = (const float*)d_in[2];
    const float* wro = (const float*)d_in[3];
    const float* bro = (const float*)d_in[4];
    const int*   ss  = (const int*)d_in[5];
    const int*   se  = (const int*)d_in[6];
    float* out = (float*)d_out;

    uintptr_t base = (uintptr_t)d_ws;
    size_t off = 0;
    auto take = [&](size_t bytes) {
        size_t o = off;
        off = (off + bytes + 255) & ~(size_t)255;
        return (void*)(base + o);
    };
    uint32_t* xbits = (uint32_t*)take((size_t)B_DIM * NIN * NWORDS * 4);
    uint32_t* WdT   = (uint32_t*)take((size_t)NIN * NHID * 4);
    (void)ws_size;

    pack_bits_kernel<<<256, 128, 0, stream>>>(x, xbits);
    pack_wd_kernel<<<512, 256, 0, stream>>>(W, drw, WdT);
    init_out_kernel<<<5, 256, 0, stream>>>(out, bro);
    fused_kernel<<<512, 512, 0, stream>>>(WdT, xbits, out, wro, ss, se);
}

// Round 5
// 320.669 us; speedup vs baseline: 7.0512x; 1.3453x over previous
//
#include <hip/hip_runtime.h>
#include <cstdint>

#define B_DIM 32
#define T_DIM 1024
#define NIN 128
#define NPAIR 64    // i-pairs
#define NHID 1024
#define KSLOT 8
#define NWORDS 34   // 2 guard words (64 zero bits) + 32 data words
#define WAVES 8
#define CHUNKS 32
#define ROUNDS (CHUNKS / WAVES)
#define WSCALE 8192.0f

typedef short short2v __attribute__((ext_vector_type(2)));

// 2 x i16 MAC in one instruction (v_dot2_i32_i16). Fallback preserves semantics.
__device__ __forceinline__ int dot2acc(uint32_t sel, uint32_t wq, int acc) {
#if __has_builtin(__builtin_amdgcn_sdot2)
    union { uint32_t u; short2v s; } a, b;
    a.u = sel; b.u = wq;
    return __builtin_amdgcn_sdot2(a.s, b.s, acc, false);
#else
    return acc + (int)(short)(sel & 0xFFFFu) * (int)(short)(wq & 0xFFFFu)
               + (int)(short)(sel >> 16)     * (int)(short)(wq >> 16);
#endif
}

// w1 = [u.b0,u.b1,v.b0,v.b1], w2 = [u.b2,u.b3,v.b2,v.b3] via v_perm_b32
__device__ __forceinline__ uint32_t combine_lo(uint32_t u, uint32_t v) {
#if __has_builtin(__builtin_amdgcn_perm)
    return __builtin_amdgcn_perm(v, u, 0x05040100u);   // src0=v, src1=u
#else
    return (u & 0xFFFFu) | (v << 16);
#endif
}
__device__ __forceinline__ uint32_t combine_hi(uint32_t u, uint32_t v) {
#if __has_builtin(__builtin_amdgcn_perm)
    return __builtin_amdgcn_perm(v, u, 0x07060302u);
#else
    return (u >> 16) | (v & 0xFFFF0000u);
#endif
}

// ---------------- merged prep kernel ----------------
// blocks   0..127: pack spike bits   xbits[b][i][w]
// blocks 128..383: pack (W,d) pairs  dpair[i2][h], wqpair[i2][h]
// blocks 384..389: init out (logits = bias, totals = 0)
__global__ void prep_kernel(const float* __restrict__ x, const float* __restrict__ W,
                            const float* __restrict__ draw, const float* __restrict__ b_ro,
                            uint32_t* __restrict__ xbits, uint32_t* __restrict__ dpair,
                            uint32_t* __restrict__ wqpair, float* __restrict__ out) {
    int blk = blockIdx.x, tid = threadIdx.x;
    if (blk < 128) {
        int b = blk >> 2, quarter = blk & 3;
        int i = tid & 127, half = tid >> 7;
        const float* xp = x + (size_t)b * T_DIM * NIN + i;
        uint32_t* colp = xbits + ((size_t)b * NIN + i) * NWORDS;
        if (quarter == 0 && half == 0) { colp[0] = 0u; colp[1] = 0u; }
        int w0 = quarter * 8 + half * 4;
        for (int w = w0; w < w0 + 4; ++w) {
            uint32_t word = 0;
            #pragma unroll 4
            for (int bit = 0; bit < 32; ++bit) {
                float xv = xp[(size_t)(w * 32 + bit) * NIN];  // lanes = consecutive i
                word |= (xv != 0.0f) ? (1u << bit) : 0u;
            }
            colp[2 + w] = word;
        }
    } else if (blk < 384) {
        int idx = (blk - 128) * 256 + tid;      // 65536 = i2*1024 + h
        int i2 = idx >> 10, h = idx & 1023;
        float w0 = W[(size_t)h * NIN + 2 * i2];
        float w1 = W[(size_t)h * NIN + 2 * i2 + 1];
        float r0 = draw[(size_t)h * NIN + 2 * i2];
        float r1 = draw[(size_t)h * NIN + 2 * i2 + 1];
        int d0 = (int)rintf(50.0f / (1.0f + expf(-r0)));   // RNE matches jnp.round
        int d1 = (int)rintf(50.0f / (1.0f + expf(-r1)));
        int q0 = (int)rintf(fminf(fmaxf(w0 * WSCALE, -32767.0f), 32767.0f));
        int q1 = (int)rintf(fminf(fmaxf(w1 * WSCALE, -32767.0f), 32767.0f));
        dpair[idx]  = (uint32_t)d0 | ((uint32_t)d1 << 8);
        wqpair[idx] = ((uint32_t)q0 & 0xFFFFu) | ((uint32_t)q1 << 16);
    } else {
        int idx = (blk - 384) * 256 + tid;      // 1280 outputs
        if (idx < B_DIM * KSLOT) out[idx] = b_ro[0];
        else if (idx < B_DIM * KSLOT + T_DIM) out[idx] = 0.0f;
    }
}

// ---------------- fused sdot2 bit-ladder + wave-relay LIF ----------------
// block = (b, hg of 64 h), 512 threads = 8 waves, grid 512 -> 2 blocks/CU (4 waves/SIMD).
// Wave sub computes I (acc[32] i32) for chunk c = 8r+sub, then relays LIF state through LDS.
__global__ __launch_bounds__(512, 4) void fused_kernel(
    const uint32_t* __restrict__ dpair, const uint32_t* __restrict__ wqpair,
    const uint32_t* __restrict__ xbits, float* __restrict__ out,
    const float* __restrict__ w_ro, const int* __restrict__ ss, const int* __restrict__ se) {
    __shared__ uint32_t lds_x[NIN * NWORDS];   // [i][w]   17 KB
    __shared__ uint32_t lds_dp[NPAIR * 64];    // [i2][hl] 16 KB
    __shared__ uint32_t lds_wq[NPAIR * 64];    // [i2][hl] 16 KB
    __shared__ float st_v[64];
    __shared__ float st_rf[64];
    __shared__ float st_sacc[KSLOT][64];
    __shared__ int   flag;

    int bx = blockIdx.x;
    int hg = bx & 15;
    int b  = bx >> 4;
    int tid  = threadIdx.x;
    int lane = tid & 63;
    int sub  = tid >> 6;
    int hbase = hg * 64;

    for (int idx = tid; idx < NIN * NWORDS; idx += 512)
        lds_x[idx] = xbits[(size_t)b * NIN * NWORDS + idx];
    for (int idx = tid; idx < NPAIR * 64; idx += 512) {
        int i2 = idx >> 6, hl = idx & 63;
        lds_dp[idx] = dpair[(size_t)i2 * NHID + hbase + hl];
        lds_wq[idx] = wqpair[(size_t)i2 * NHID + hbase + hl];
    }
    if (tid < 64) { st_v[tid] = 0.0f; st_rf[tid] = 0.0f; }
    ((float*)st_sacc)[tid] = 0.0f;
    if (tid == 0) flag = 0;
    __syncthreads();

    int st_[KSLOT], en_[KSLOT];
    #pragma unroll
    for (int k = 0; k < KSLOT; ++k) {
        st_[k] = __builtin_amdgcn_readfirstlane(ss[k]);
        en_[k] = __builtin_amdgcn_readfirstlane(se[k]);
    }
    float wr = w_ro[hbase + lane];

    float v = 0.0f, rf = 0.0f;
    float sacc[KSLOT];
    #pragma unroll
    for (int k = 0; k < KSLOT; ++k) sacc[k] = 0.0f;

    for (int r = 0; r < ROUNDS; ++r) {
        int c  = r * WAVES + sub;
        int t0 = c * 32;
        int acc[32];
        #pragma unroll
        for (int k = 0; k < 32; ++k) acc[k] = 0;
        #pragma unroll 2
        for (int i2 = 0; i2 < NPAIR; ++i2) {
            uint32_t dp = lds_dp[(i2 << 6) | lane];
            uint32_t wq = lds_wq[(i2 << 6) | lane];
            int d0 = (int)(dp & 63u);
            int d1 = (int)((dp >> 8) & 63u);
            // shifted 32-bit spike windows for i = 2*i2 and 2*i2+1
            int sp0 = t0 + 63 - d0;                 // +64 guard bits, >= 13
            int idx0 = (i2 * 2) * NWORDS + (sp0 >> 5);
            uint32_t lo0 = lds_x[idx0], hi0 = lds_x[idx0 + 1];
            uint32_t u = (uint32_t)(((((uint64_t)hi0) << 32) | lo0) >> (sp0 & 31));
            int sp1 = t0 + 63 - d1;
            int idx1 = (i2 * 2 + 1) * NWORDS + (sp1 >> 5);
            uint32_t lo1 = lds_x[idx1], hi1 = lds_x[idx1 + 1];
            uint32_t vv = (uint32_t)(((((uint64_t)hi1) << 32) | lo1) >> (sp1 & 31));
            // interleave: bit k & bit k+16 of w1 = (u_k, v_k); of w2 = (u_{k+16}, v_{k+16})
            uint32_t w1 = combine_lo(u, vv);
            uint32_t w2 = combine_hi(u, vv);
            #pragma unroll
            for (int k = 0; k < 16; ++k) {
                uint32_t s1_ = (w1 >> k) & 0x00010001u;   // packed i16 {0,1} pair
                acc[k]      = dot2acc(s1_, wq, acc[k]);   // += u_k*wq0 + v_k*wq1
                uint32_t s2_ = (w2 >> k) & 0x00010001u;
                acc[16 + k] = dot2acc(s2_, wq, acc[16 + k]);
            }
        }
        // ---- relay: wait for token ----
        while (__builtin_amdgcn_readfirstlane(*(volatile int*)&flag) != c)
            __builtin_amdgcn_s_sleep(1);
        v  = st_v[lane];
        rf = st_rf[lane];
        #pragma unroll
        for (int k = 0; k < KSLOT; ++k) sacc[k] = st_sacc[k][lane];
        #pragma unroll
        for (int k = 0; k < 32; ++k) {
            float I = (float)acc[k] * (1.0f / WSCALE);
            int t = t0 + k;
            bool active = (rf <= 0.0f);
            float vupd = v + 0.1f * (I - v);
            float vn = active ? vupd : v;
            bool spike = active && (vn >= 1.0f);
            unsigned long long bal = __ballot(spike);
            if (bal != 0ULL) {                      // rare path (~14 sigma margin)
                if (spike) {
                    vn = 0.0f;
                    #pragma unroll
                    for (int k2 = 0; k2 < KSLOT; ++k2)
                        if (t >= st_[k2] && t < en_[k2]) sacc[k2] += 1.0f;
                }
                rf = spike ? 2.0f : fmaxf(rf - 1.0f, 0.0f);
                if (lane == 0) atomicAdd(&out[B_DIM * KSLOT + t], (float)__popcll(bal));
            } else {
                rf = fmaxf(rf - 1.0f, 0.0f);
            }
            v = vn;
        }
        st_v[lane]  = v;
        st_rf[lane] = rf;
        #pragma unroll
        for (int k = 0; k < KSLOT; ++k) st_sacc[k][lane] = sacc[k];
        __threadfence_block();
        if (lane == 0) *(volatile int*)&flag = c + 1;
    }
    if (sub == WAVES - 1) {
        #pragma unroll
        for (int k = 0; k < KSLOT; ++k) {
            float val = sacc[k] * wr;
            #pragma unroll
            for (int o = 32; o > 0; o >>= 1) val += __shfl_down(val, o);
            if (lane == 0) atomicAdd(&out[b * KSLOT + k], val);
        }
    }
}

extern "C" void kernel_launch(void* const* d_in, const int* in_sizes, int n_in,
                              void* d_out, int out_size, void* d_ws, size_t ws_size,
                              hipStream_t stream) {
    const float* x   = (const float*)d_in[0];
    const float* W   = (const float*)d_in[1];
    const float* drw = (const float*)d_in[2];
    const float* wro = (const float*)d_in[3];
    const float* bro = (const float*)d_in[4];
    const int*   ss  = (const int*)d_in[5];
    const int*   se  = (const int*)d_in[6];
    float* out = (float*)d_out;

    uintptr_t base = (uintptr_t)d_ws;
    size_t off = 0;
    auto take = [&](size_t bytes) {
        size_t o = off;
        off = (off + bytes + 255) & ~(size_t)255;
        return (void*)(base + o);
    };
    uint32_t* xbits  = (uint32_t*)take((size_t)B_DIM * NIN * NWORDS * 4);
    uint32_t* dpair  = (uint32_t*)take((size_t)NPAIR * NHID * 4);
    uint32_t* wqpair = (uint32_t*)take((size_t)NPAIR * NHID * 4);
    (void)ws_size;

    prep_kernel<<<390, 256, 0, stream>>>(x, W, drw, bro, xbits, dpair, wqpair, out);
    fused_kernel<<<512, 512, 0, stream>>>(dpair, wqpair, xbits, out, wro, ss, se);
}

// Round 6
// 234.495 us; speedup vs baseline: 9.6424x; 1.3675x over previous
//
#include <hip/hip_runtime.h>
#include <cstdint>

#define B_DIM 32
#define T_DIM 1024
#define NIN 128
#define NQUAD 32    // i-quads
#define NHID 1024
#define KSLOT 8
#define NWORDS 34   // 2 guard words (64 zero bits) + 32 data words
#define WAVES 8
#define CHUNKS 32
#define ROUNDS (CHUNKS / WAVES)
#define WSCALE 256.0f

// 4 x i8 MAC in one instruction (v_dot4_i32_i8). Fallback preserves semantics.
__device__ __forceinline__ int dot4acc(uint32_t sel, uint32_t wq, int acc) {
#if __has_builtin(__builtin_amdgcn_sdot4)
    return __builtin_amdgcn_sdot4((int)sel, (int)wq, acc, false);
#else
    #pragma unroll
    for (int j = 0; j < 4; ++j)
        acc += (int)(signed char)((sel >> (8 * j)) & 0xFF) *
               (int)(signed char)((wq  >> (8 * j)) & 0xFF);
    return acc;
#endif
}

__device__ __forceinline__ uint32_t permb(uint32_t hi, uint32_t lo, uint32_t sel) {
#if __has_builtin(__builtin_amdgcn_perm)
    return __builtin_amdgcn_perm(hi, lo, sel);   // S0=hi(bytes 7..4), S1=lo(bytes 3..0)
#else
    union { uint32_t w[2]; unsigned char b[8]; } src;
    src.w[0] = lo; src.w[1] = hi;
    uint32_t r = 0;
    for (int n = 0; n < 4; ++n) r |= (uint32_t)src.b[(sel >> (8 * n)) & 7] << (8 * n);
    return r;
#endif
}

__device__ __forceinline__ uint32_t funnel32(uint32_t hi, uint32_t lo, uint32_t sh) {
#if __has_builtin(__builtin_amdgcn_alignbit)
    return __builtin_amdgcn_alignbit(hi, lo, sh);   // ((hi:lo) >> (sh&31)) low 32
#else
    return (uint32_t)(((((uint64_t)hi) << 32) | lo) >> (sh & 31));
#endif
}

// ---------------- merged prep kernel ----------------
// blocks   0..127: pack spike bits   xbits[b][i][w]
// blocks 128..255: pack delays/weights  dq4[i4][h] (4x u8 delay), wq4[i4][h] (4x i8 W*256)
// blocks 256..260: init out (logits = bias, totals = 0)
__global__ void prep_kernel(const float* __restrict__ x, const float* __restrict__ W,
                            const float* __restrict__ draw, const float* __restrict__ b_ro,
                            uint32_t* __restrict__ xbits, uint32_t* __restrict__ dq4,
                            uint32_t* __restrict__ wq4, float* __restrict__ out) {
    int blk = blockIdx.x, tid = threadIdx.x;
    if (blk < 128) {
        int b = blk >> 2, quarter = blk & 3;
        int i = tid & 127, half = tid >> 7;
        const float* xp = x + (size_t)b * T_DIM * NIN + i;
        uint32_t* colp = xbits + ((size_t)b * NIN + i) * NWORDS;
        if (quarter == 0 && half == 0) { colp[0] = 0u; colp[1] = 0u; }
        int w0 = quarter * 8 + half * 4;
        for (int w = w0; w < w0 + 4; ++w) {
            uint32_t word = 0;
            #pragma unroll 4
            for (int bit = 0; bit < 32; ++bit) {
                float xv = xp[(size_t)(w * 32 + bit) * NIN];  // lanes = consecutive i
                word |= (xv != 0.0f) ? (1u << bit) : 0u;
            }
            colp[2 + w] = word;
        }
    } else if (blk < 256) {
        int idx = (blk - 128) * 256 + tid;      // 32768 = i4*1024 + h
        int i4 = idx >> 10, h = idx & 1023;
        const float* Wp = W    + (size_t)h * NIN + 4 * i4;
        const float* Rp = draw + (size_t)h * NIN + 4 * i4;
        uint32_t dq = 0, wq = 0;
        #pragma unroll
        for (int j = 0; j < 4; ++j) {
            int d = (int)rintf(50.0f / (1.0f + expf(-Rp[j])));   // RNE matches jnp.round
            int q = (int)rintf(fminf(fmaxf(Wp[j] * WSCALE, -127.0f), 127.0f));
            dq |= (uint32_t)d << (8 * j);
            wq |= ((uint32_t)q & 0xFFu) << (8 * j);
        }
        dq4[idx] = dq;
        wq4[idx] = wq;
    } else {
        int idx = (blk - 256) * 256 + tid;      // 1280 outputs
        if (idx < B_DIM * KSLOT) out[idx] = b_ro[0];
        else if (idx < B_DIM * KSLOT + T_DIM) out[idx] = 0.0f;
    }
}

// ---------------- fused sdot4 bit-ladder + wave-relay LIF ----------------
// block = (b, hg of 64 h), 512 threads = 8 waves, grid 512 -> 2 blocks/CU (4 waves/SIMD).
// Wave sub computes I (acc[32] i32) for chunk c = 8r+sub via byte-interleaved windows +
// v_dot4_i32_i8, then relays LIF state (v, rf, sacc) wave->wave through LDS.
__global__ __launch_bounds__(512, 4) void fused_kernel(
    const uint32_t* __restrict__ dq4, const uint32_t* __restrict__ wq4,
    const uint32_t* __restrict__ xbits, float* __restrict__ out,
    const float* __restrict__ w_ro, const int* __restrict__ ss, const int* __restrict__ se) {
    __shared__ uint32_t lds_x[NIN * NWORDS];   // [i][w]    17 KB
    __shared__ uint32_t lds_dq[NQUAD * 64];    // [i4][hl]   8 KB
    __shared__ uint32_t lds_wq[NQUAD * 64];    // [i4][hl]   8 KB
    __shared__ float st_v[64];
    __shared__ float st_rf[64];
    __shared__ float st_sacc[KSLOT][64];
    __shared__ int   flag;

    int bx = blockIdx.x;
    int hg = bx & 15;
    int b  = bx >> 4;
    int tid  = threadIdx.x;
    int lane = tid & 63;
    int sub  = tid >> 6;
    int hbase = hg * 64;

    for (int idx = tid; idx < NIN * NWORDS; idx += 512)
        lds_x[idx] = xbits[(size_t)b * NIN * NWORDS + idx];
    for (int idx = tid; idx < NQUAD * 64; idx += 512) {
        int i4 = idx >> 6, hl = idx & 63;
        lds_dq[idx] = dq4[(size_t)i4 * NHID + hbase + hl];
        lds_wq[idx] = wq4[(size_t)i4 * NHID + hbase + hl];
    }
    if (tid < 64) { st_v[tid] = 0.0f; st_rf[tid] = 0.0f; }
    ((float*)st_sacc)[tid] = 0.0f;
    if (tid == 0) flag = 0;
    __syncthreads();

    int st_[KSLOT], en_[KSLOT];
    #pragma unroll
    for (int k = 0; k < KSLOT; ++k) {
        st_[k] = __builtin_amdgcn_readfirstlane(ss[k]);
        en_[k] = __builtin_amdgcn_readfirstlane(se[k]);
    }
    float wr = w_ro[hbase + lane];

    float v = 0.0f, rf = 0.0f;
    float sacc[KSLOT];
    #pragma unroll
    for (int k = 0; k < KSLOT; ++k) sacc[k] = 0.0f;

    for (int rl = 0; rl < ROUNDS; ++rl) {
        int c  = __builtin_amdgcn_readfirstlane(rl * WAVES + sub);
        int t0 = c * 32;
        int acc[32];
        #pragma unroll
        for (int k = 0; k < 32; ++k) acc[k] = 0;
        #pragma unroll 2
        for (int i4 = 0; i4 < NQUAD; ++i4) {
            uint32_t dq = lds_dq[(i4 << 6) | lane];
            uint32_t wq = lds_wq[(i4 << 6) | lane];
            uint32_t win[4];
            #pragma unroll
            for (int j = 0; j < 4; ++j) {
                int d   = (int)((dq >> (8 * j)) & 63u);
                int sp0 = 63 - d;                              // in [13,63]
                // word index: i*NWORDS + c + (sp0>>5); window bit k = x[b, t0+k-1-d, i]
                int wbase = (4 * i4 + j) * NWORDS + c + (sp0 >> 5);
                uint32_t lo = lds_x[wbase];                    // adjacent -> ds_read2_b32
                uint32_t hi = lds_x[wbase + 1];
                win[j] = funnel32(hi, lo, (uint32_t)(sp0 & 31));
            }
            // byte-interleave 4 streams: W_g byte j = win[j] byte g
            uint32_t A  = permb(win[1], win[0], 0x05010400u);  // [w0b0,w1b0,w0b1,w1b1]
            uint32_t Bw = permb(win[1], win[0], 0x07030602u);  // [w0b2,w1b2,w0b3,w1b3]
            uint32_t C  = permb(win[3], win[2], 0x05010400u);
            uint32_t Dw = permb(win[3], win[2], 0x07030602u);
            uint32_t W0 = permb(C,  A,  0x05040100u);          // bytes g=0 of streams 0..3
            uint32_t W1 = permb(C,  A,  0x07060302u);          // g=1
            uint32_t W2 = permb(Dw, Bw, 0x05040100u);          // g=2
            uint32_t W3 = permb(Dw, Bw, 0x07060302u);          // g=3
            #pragma unroll
            for (int kk = 0; kk < 8; ++kk) {
                acc[kk]      = dot4acc((W0 >> kk) & 0x01010101u, wq, acc[kk]);
                acc[8 + kk]  = dot4acc((W1 >> kk) & 0x01010101u, wq, acc[8 + kk]);
                acc[16 + kk] = dot4acc((W2 >> kk) & 0x01010101u, wq, acc[16 + kk]);
                acc[24 + kk] = dot4acc((W3 >> kk) & 0x01010101u, wq, acc[24 + kk]);
            }
        }
        // ---- relay: wait for token ----
        while (__builtin_amdgcn_readfirstlane(*(volatile int*)&flag) != c)
            __builtin_amdgcn_s_sleep(1);
        v  = st_v[lane];
        rf = st_rf[lane];
        #pragma unroll
        for (int k = 0; k < KSLOT; ++k) sacc[k] = st_sacc[k][lane];
        #pragma unroll
        for (int k = 0; k < 32; ++k) {
            float I = (float)acc[k] * (1.0f / WSCALE);
            int t = t0 + k;
            bool active = (rf <= 0.0f);
            float vupd = v + 0.1f * (I - v);
            float vn = active ? vupd : v;
            bool spike = active && (vn >= 1.0f);
            unsigned long long bal = __ballot(spike);
            if (bal != 0ULL) {                      // rare path (~14 sigma margin)
                if (spike) {
                    vn = 0.0f;
                    #pragma unroll
                    for (int k2 = 0; k2 < KSLOT; ++k2)
                        if (t >= st_[k2] && t < en_[k2]) sacc[k2] += 1.0f;
                }
                rf = spike ? 2.0f : fmaxf(rf - 1.0f, 0.0f);
                if (lane == 0) atomicAdd(&out[B_DIM * KSLOT + t], (float)__popcll(bal));
            } else {
                rf = fmaxf(rf - 1.0f, 0.0f);
            }
            v = vn;
        }
        st_v[lane]  = v;
        st_rf[lane] = rf;
        #pragma unroll
        for (int k = 0; k < KSLOT; ++k) st_sacc[k][lane] = sacc[k];
        __threadfence_block();
        if (lane == 0) *(volatile int*)&flag = c + 1;
    }
    if (sub == WAVES - 1) {
        #pragma unroll
        for (int k = 0; k < KSLOT; ++k) {
            float val = sacc[k] * wr;
            #pragma unroll
            for (int o = 32; o > 0; o >>= 1) val += __shfl_down(val, o);
            if (lane == 0) atomicAdd(&out[b * KSLOT + k], val);
        }
    }
}

extern "C" void kernel_launch(void* const* d_in, const int* in_sizes, int n_in,
                              void* d_out, int out_size, void* d_ws, size_t ws_size,
                              hipStream_t stream) {
    const float* x   = (const float*)d_in[0];
    const float* W   = (const float*)d_in[1];
    const float* drw = (const float*)d_in[2];
    const float* wro = (const float*)d_in[3];
    const float* bro = (const float*)d_in[4];
    const int*   ss  = (const int*)d_in[5];
    const int*   se  = (const int*)d_in[6];
    float* out = (float*)d_out;

    uintptr_t base = (uintptr_t)d_ws;
    size_t off = 0;
    auto take = [&](size_t bytes) {
        size_t o = off;
        off = (off + bytes + 255) & ~(size_t)255;
        return (void*)(base + o);
    };
    uint32_t* xbits = (uint32_t*)take((size_t)B_DIM * NIN * NWORDS * 4);
    uint32_t* dq4   = (uint32_t*)take((size_t)NQUAD * NHID * 4);
    uint32_t* wq4   = (uint32_t*)take((size_t)NQUAD * NHID * 4);
    (void)ws_size;

    prep_kernel<<<261, 256, 0, stream>>>(x, W, drw, bro, xbits, dq4, wq4, out);
    fused_kernel<<<512, 512, 0, stream>>>(dq4, wq4, xbits, out, wro, ss, se);
}

// Round 7
// 215.160 us; speedup vs baseline: 10.5089x; 1.0899x over previous
//
#include <hip/hip_runtime.h>
#include <cstdint>

#define B_DIM 32
#define T_DIM 1024
#define NIN 128
#define NG 16       // i-groups of 8
#define NHID 1024
#define KSLOT 8
#define NWORDS 34   // 2 guard words (64 zero bits) + 32 data words
#define WAVES 16
#define CHUNKS 32
#define ROUNDS (CHUNKS / WAVES)
#define WSCALE 16.0f

// 8 x i4 MAC in one instruction (v_dot8_i32_i4). Fallback preserves semantics.
__device__ __forceinline__ int dot8acc(uint32_t sel, uint32_t wq, int acc) {
#if __has_builtin(__builtin_amdgcn_sdot8)
    return __builtin_amdgcn_sdot8((int)sel, (int)wq, acc, false);
#else
    #pragma unroll
    for (int m = 0; m < 8; ++m) {
        int s = (int)((sel >> (4 * m)) & 0xF);            // 0 or 1
        int q = ((int)((wq >> (4 * m)) & 0xF) << 28) >> 28; // sign-extend i4
        acc += s * q;
    }
    return acc;
#endif
}

__device__ __forceinline__ uint32_t permb(uint32_t hi, uint32_t lo, uint32_t sel) {
#if __has_builtin(__builtin_amdgcn_perm)
    return __builtin_amdgcn_perm(hi, lo, sel);   // S0=hi(bytes 7..4), S1=lo(bytes 3..0)
#else
    union { uint32_t w[2]; unsigned char b[8]; } src;
    src.w[0] = lo; src.w[1] = hi;
    uint32_t r = 0;
    for (int n = 0; n < 4; ++n) r |= (uint32_t)src.b[(sel >> (8 * n)) & 7] << (8 * n);
    return r;
#endif
}

__device__ __forceinline__ uint32_t funnel32(uint32_t hi, uint32_t lo, uint32_t sh) {
#if __has_builtin(__builtin_amdgcn_alignbit)
    return __builtin_amdgcn_alignbit(hi, lo, sh);   // ((hi:lo) >> (sh&31)) low 32
#else
    return (uint32_t)(((((uint64_t)hi) << 32) | lo) >> (sh & 31));
#endif
}

// ---------------- merged prep kernel ----------------
// blocks   0..511: pack spike bits — ONE thread per (b, i, word): 32 independent loads,
//                  fully unrolled (round-6 lesson: 128 latency-exposed loads/thread on
//                  128 blocks made prep ~55 us).
// blocks 512..575: pack delays (8 x u8 -> uint2) + weights (8 x i4 nibbles, order
//                  [0,4,1,5,2,6,3,7] to match the nibble-interleave in fused_kernel)
// blocks 576..580: init out (logits = bias, totals = 0)
__global__ void prep_kernel(const float* __restrict__ x, const float* __restrict__ W,
                            const float* __restrict__ draw, const float* __restrict__ b_ro,
                            uint32_t* __restrict__ xbits, uint2* __restrict__ dq2,
                            uint32_t* __restrict__ wq8, float* __restrict__ out) {
    int blk = blockIdx.x, tid = threadIdx.x;
    if (blk < 512) {
        int idx = blk * 256 + tid;        // 131072 = b*4096 + w*128 + i
        int b = idx >> 12, w = (idx >> 7) & 31, i = idx & 127;
        const float* xp = x + (size_t)b * T_DIM * NIN + (size_t)w * 32 * NIN + i;
        uint32_t word = 0;
        #pragma unroll
        for (int bit = 0; bit < 32; ++bit) {
            float xv = xp[(size_t)bit * NIN];   // lanes = consecutive i -> coalesced
            word |= (xv != 0.0f) ? (1u << bit) : 0u;
        }
        uint32_t* colp = xbits + ((size_t)b * NIN + i) * NWORDS;
        colp[2 + w] = word;
        if (w == 0) { colp[0] = 0u; colp[1] = 0u; }      // guard words
    } else if (blk < 576) {
        int idx = (blk - 512) * 256 + tid;    // 16384 = g*1024 + h
        int g = idx >> 10, h = idx & 1023;
        const float* Wp = W    + (size_t)h * NIN + 8 * g;
        const float* Rp = draw + (size_t)h * NIN + 8 * g;
        uint32_t d0 = 0, d1 = 0, wq = 0;
        const int ordm[8] = {0, 4, 1, 5, 2, 6, 3, 7};
        #pragma unroll
        for (int j = 0; j < 4; ++j) {
            d0 |= (uint32_t)(int)rintf(50.0f / (1.0f + expf(-Rp[j])))     << (8 * j);
            d1 |= (uint32_t)(int)rintf(50.0f / (1.0f + expf(-Rp[4 + j]))) << (8 * j);
        }
        #pragma unroll
        for (int m = 0; m < 8; ++m) {
            int q = (int)rintf(fminf(fmaxf(Wp[ordm[m]] * WSCALE, -8.0f), 7.0f));
            wq |= ((uint32_t)q & 0xFu) << (4 * m);
        }
        dq2[(size_t)g * NHID + h] = make_uint2(d0, d1);
        wq8[(size_t)g * NHID + h] = wq;
    } else {
        int idx = (blk - 576) * 256 + tid;    // 1280 outputs
        if (idx < B_DIM * KSLOT) out[idx] = b_ro[0];
        else if (idx < B_DIM * KSLOT + T_DIM) out[idx] = 0.0f;
    }
}

// ---------------- fused sdot8 nibble-ladder + wave-relay LIF ----------------
// block = (b, hg of 64 h), 1024 threads = 16 waves, grid 512 -> 2 blocks/CU,
// launch_bounds(1024,8) -> 32 waves/CU (100% nominal occupancy, VGPR <= 64).
// Wave sub computes I (acc[32] i32) for chunk c = 16*rl + sub via nibble-interleaved
// spike windows + v_dot8_i32_i4, then relays LIF state wave->wave through LDS.
__global__ __launch_bounds__(1024, 8) void fused_kernel(
    const uint2* __restrict__ dq2, const uint32_t* __restrict__ wq8,
    const uint32_t* __restrict__ xbits, float* __restrict__ out,
    const float* __restrict__ w_ro, const int* __restrict__ ss, const int* __restrict__ se) {
    __shared__ uint32_t lds_x[NIN * NWORDS];  // [i][w]   17 KB
    __shared__ uint2    lds_d2[NG * 64];      // [g][hl]   8 KB (8 x u8 delays)
    __shared__ uint32_t lds_w[NG * 64];       // [g][hl]   4 KB (8 x i4 weights)
    __shared__ float st_v[64];
    __shared__ float st_rf[64];
    __shared__ float st_sacc[KSLOT][64];
    __shared__ int   flag;

    int bx = blockIdx.x;
    int hg = bx & 15;
    int b  = bx >> 4;
    int tid  = threadIdx.x;
    int lane = tid & 63;
    int sub  = tid >> 6;
    int hbase = hg * 64;

    for (int idx = tid; idx < NIN * NWORDS; idx += 1024)
        lds_x[idx] = xbits[(size_t)b * NIN * NWORDS + idx];
    if (tid < NG * 64) {
        int g = tid >> 6, hl = tid & 63;
        lds_d2[tid] = dq2[(size_t)g * NHID + hbase + hl];
        lds_w[tid]  = wq8[(size_t)g * NHID + hbase + hl];
    }
    if (tid < 64) { st_v[tid] = 0.0f; st_rf[tid] = 0.0f; }
    if (tid < KSLOT * 64) ((float*)st_sacc)[tid] = 0.0f;
    if (tid == 0) flag = 0;
    __syncthreads();

    int st_[KSLOT], en_[KSLOT];
    #pragma unroll
    for (int k = 0; k < KSLOT; ++k) {
        st_[k] = __builtin_amdgcn_readfirstlane(ss[k]);
        en_[k] = __builtin_amdgcn_readfirstlane(se[k]);
    }

    float v = 0.0f, rf = 0.0f;
    float sacc[KSLOT];
    #pragma unroll
    for (int k = 0; k < KSLOT; ++k) sacc[k] = 0.0f;

    for (int rl = 0; rl < ROUNDS; ++rl) {
        int c  = __builtin_amdgcn_readfirstlane(rl * WAVES + sub);
        int t0 = c * 32;
        int acc[32];
        #pragma unroll
        for (int k = 0; k < 32; ++k) acc[k] = 0;
        #pragma unroll 2
        for (int g = 0; g < NG; ++g) {
            uint2 dd    = lds_d2[(g << 6) | lane];
            uint32_t wq = lds_w[(g << 6) | lane];
            uint32_t P0, P1, P2, P3, X[8];
            {   // streams 8g..8g+3: windows (bit k = spike at t0+k, delay folded)
                uint32_t win[4];
                #pragma unroll
                for (int j = 0; j < 4; ++j) {
                    int d  = (int)((dd.x >> (8 * j)) & 0xFFu);
                    int sp = 63 - d;                          // in [13,63]
                    int wbase = (8 * g + j) * NWORDS + c + (sp >> 5);
                    win[j] = funnel32(lds_x[wbase + 1], lds_x[wbase], (uint32_t)sp);
                }
                uint32_t A  = permb(win[1], win[0], 0x05010400u);
                uint32_t Bv = permb(win[1], win[0], 0x07030602u);
                uint32_t Cv = permb(win[3], win[2], 0x05010400u);
                uint32_t Dv = permb(win[3], win[2], 0x07030602u);
                P0 = permb(Cv, A,  0x05040100u);   // byte j = stream j, byte 0
                P1 = permb(Cv, A,  0x07060302u);
                P2 = permb(Dv, Bv, 0x05040100u);
                P3 = permb(Dv, Bv, 0x07060302u);
            }
            {   // streams 8g+4..8g+7, then nibble-interleave via bfi pattern
                uint32_t win[4];
                #pragma unroll
                for (int j = 0; j < 4; ++j) {
                    int d  = (int)((dd.y >> (8 * j)) & 0xFFu);
                    int sp = 63 - d;
                    int wbase = (8 * g + 4 + j) * NWORDS + c + (sp >> 5);
                    win[j] = funnel32(lds_x[wbase + 1], lds_x[wbase], (uint32_t)sp);
                }
                uint32_t A  = permb(win[1], win[0], 0x05010400u);
                uint32_t Bv = permb(win[1], win[0], 0x07030602u);
                uint32_t Cv = permb(win[3], win[2], 0x05010400u);
                uint32_t Dv = permb(win[3], win[2], 0x07030602u);
                uint32_t Q0 = permb(Cv, A,  0x05040100u);
                uint32_t Q1 = permb(Cv, A,  0x07060302u);
                uint32_t Q2 = permb(Dv, Bv, 0x05040100u);
                uint32_t Q3 = permb(Dv, Bv, 0x07060302u);
                // X[2q]: nibble m = bit group; nibble order [0,4,1,5,2,6,3,7] matches wq8
                X[0] = (P0 & 0x0F0F0F0Fu) | ((Q0 << 4) & 0xF0F0F0F0u);   // v_bfi_b32
                X[1] = ((P0 >> 4) & 0x0F0F0F0Fu) | (Q0 & 0xF0F0F0F0u);
                X[2] = (P1 & 0x0F0F0F0Fu) | ((Q1 << 4) & 0xF0F0F0F0u);
                X[3] = ((P1 >> 4) & 0x0F0F0F0Fu) | (Q1 & 0xF0F0F0F0u);
                X[4] = (P2 & 0x0F0F0F0Fu) | ((Q2 << 4) & 0xF0F0F0F0u);
                X[5] = ((P2 >> 4) & 0x0F0F0F0Fu) | (Q2 & 0xF0F0F0F0u);
                X[6] = (P3 & 0x0F0F0F0Fu) | ((Q3 << 4) & 0xF0F0F0F0u);
                X[7] = ((P3 >> 4) & 0x0F0F0F0Fu) | (Q3 & 0xF0F0F0F0u);
            }
            // X[gp] bit (4m+kk) = stream order[m] spike at t0 + 4*gp + kk
            #pragma unroll
            for (int gp = 0; gp < 8; ++gp) {
                acc[4 * gp]     = dot8acc(X[gp] & 0x11111111u,        wq, acc[4 * gp]);
                acc[4 * gp + 1] = dot8acc((X[gp] >> 1) & 0x11111111u, wq, acc[4 * gp + 1]);
                acc[4 * gp + 2] = dot8acc((X[gp] >> 2) & 0x11111111u, wq, acc[4 * gp + 2]);
                acc[4 * gp + 3] = dot8acc((X[gp] >> 3) & 0x11111111u, wq, acc[4 * gp + 3]);
            }
        }
        // ---- relay: wait for token ----
        while (__builtin_amdgcn_readfirstlane(*(volatile int*)&flag) != c)
            __builtin_amdgcn_s_sleep(1);
        v  = st_v[lane];
        rf = st_rf[lane];
        #pragma unroll
        for (int k = 0; k < KSLOT; ++k) sacc[k] = st_sacc[k][lane];
        #pragma unroll
        for (int k = 0; k < 32; ++k) {
            float I = (float)acc[k] * (1.0f / WSCALE);
            int t = t0 + k;
            bool active = (rf <= 0.0f);
            float vupd = v + 0.1f * (I - v);
            float vn = active ? vupd : v;
            bool spike = active && (vn >= 1.0f);
            unsigned long long bal = __ballot(spike);
            if (bal != 0ULL) {                      // rare path (>=14 sigma margin)
                if (spike) {
                    vn = 0.0f;
                    #pragma unroll
                    for (int k2 = 0; k2 < KSLOT; ++k2)
                        if (t >= st_[k2] && t < en_[k2]) sacc[k2] += 1.0f;
                }
                rf = spike ? 2.0f : fmaxf(rf - 1.0f, 0.0f);
                if (lane == 0) atomicAdd(&out[B_DIM * KSLOT + t], (float)__popcll(bal));
            } else {
                rf = fmaxf(rf - 1.0f, 0.0f);
            }
            v = vn;
        }
        st_v[lane]  = v;
        st_rf[lane] = rf;
        #pragma unroll
        for (int k = 0; k < KSLOT; ++k) st_sacc[k][lane] = sacc[k];
        __threadfence_block();
        if (lane == 0) *(volatile int*)&flag = c + 1;
    }
    // ---- epilogue: wave owning chunk 31 holds final sacc ----
    if (sub == WAVES - 1) {
        float wr = w_ro[hbase + lane];
        #pragma unroll
        for (int k = 0; k < KSLOT; ++k) {
            float val = sacc[k] * wr;
            #pragma unroll
            for (int o = 32; o > 0; o >>= 1) val += __shfl_down(val, o);
            if (lane == 0) atomicAdd(&out[b * KSLOT + k], val);
        }
    }
}

extern "C" void kernel_launch(void* const* d_in, const int* in_sizes, int n_in,
                              void* d_out, int out_size, void* d_ws, size_t ws_size,
                              hipStream_t stream) {
    const float* x   = (const float*)d_in[0];
    const float* W   = (const float*)d_in[1];
    const float* drw = (const float*)d_in[2];
    const float* wro = (const float*)d_in[3];
    const float* bro = (const float*)d_in[4];
    const int*   ss  = (const int*)d_in[5];
    const int*   se  = (const int*)d_in[6];
    float* out = (float*)d_out;

    uintptr_t base = (uintptr_t)d_ws;
    size_t off = 0;
    auto take = [&](size_t bytes) {
        size_t o = off;
        off = (off + bytes + 255) & ~(size_t)255;
        return (void*)(base + o);
    };
    uint32_t* xbits = (uint32_t*)take((size_t)B_DIM * NIN * NWORDS * 4);
    uint2*    dq2   = (uint2*)take((size_t)NG * NHID * 8);
    uint32_t* wq8   = (uint32_t*)take((size_t)NG * NHID * 4);
    (void)ws_size;

    prep_kernel<<<581, 256, 0, stream>>>(x, W, drw, bro, xbits, dq2, wq8, out);
    fused_kernel<<<512, 1024, 0, stream>>>(dq2, wq8, xbits, out, wro, ss, se);
}

// Round 8
// 168.718 us; speedup vs baseline: 13.4016x; 1.2753x over previous
//
#include <hip/hip_runtime.h>
#include <cstdint>

#define B_DIM 32
#define T_DIM 1024
#define NIN 128
#define NG 16       // i-groups of 8
#define NHID 1024
#define KSLOT 8
#define NWORDS 34   // 2 guard words (64 zero bits) + 32 data words
#define WAVES 8
#define CHUNKS 32
#define ROUNDS (CHUNKS / WAVES)
#define WSCALE 16.0f

// 8 x i4 MAC in one instruction (v_dot8_i32_i4). Fallback preserves semantics.
__device__ __forceinline__ int dot8acc(uint32_t sel, uint32_t wq, int acc) {
#if __has_builtin(__builtin_amdgcn_sdot8)
    return __builtin_amdgcn_sdot8((int)sel, (int)wq, acc, false);
#else
    #pragma unroll
    for (int m = 0; m < 8; ++m) {
        int s = (int)((sel >> (4 * m)) & 0xF);              // 0 or 1
        int q = ((int)((wq >> (4 * m)) & 0xF) << 28) >> 28; // sign-extend i4
        acc += s * q;
    }
    return acc;
#endif
}

__device__ __forceinline__ uint32_t permb(uint32_t hi, uint32_t lo, uint32_t sel) {
#if __has_builtin(__builtin_amdgcn_perm)
    return __builtin_amdgcn_perm(hi, lo, sel);   // S0=hi(bytes 7..4), S1=lo(bytes 3..0)
#else
    union { uint32_t w[2]; unsigned char b[8]; } src;
    src.w[0] = lo; src.w[1] = hi;
    uint32_t r = 0;
    for (int n = 0; n < 4; ++n) r |= (uint32_t)src.b[(sel >> (8 * n)) & 7] << (8 * n);
    return r;
#endif
}

__device__ __forceinline__ uint32_t funnel32(uint32_t hi, uint32_t lo, uint32_t sh) {
#if __has_builtin(__builtin_amdgcn_alignbit)
    return __builtin_amdgcn_alignbit(hi, lo, sh);   // ((hi:lo) >> (sh&31)) low 32
#else
    return (uint32_t)(((((uint64_t)hi) << 32) | lo) >> (sh & 31));
#endif
}

// ---------------- merged prep kernel ----------------
// blocks   0..511: pack spike bits — one thread per (b, i, word), 32 unrolled loads
// blocks 512..575: pack delays (8 x u8 -> uint2) + weights (8 x i4 nibbles, order
//                  [0,4,1,5,2,6,3,7] to match the nibble-interleave in fused_kernel)
// blocks 576..580: init out (logits = bias, totals = 0)
__global__ void prep_kernel(const float* __restrict__ x, const float* __restrict__ W,
                            const float* __restrict__ draw, const float* __restrict__ b_ro,
                            uint32_t* __restrict__ xbits, uint2* __restrict__ dq2,
                            uint32_t* __restrict__ wq8, float* __restrict__ out) {
    int blk = blockIdx.x, tid = threadIdx.x;
    if (blk < 512) {
        int idx = blk * 256 + tid;        // 131072 = b*4096 + w*128 + i
        int b = idx >> 12, w = (idx >> 7) & 31, i = idx & 127;
        const float* xp = x + (size_t)b * T_DIM * NIN + (size_t)w * 32 * NIN + i;
        uint32_t word = 0;
        #pragma unroll
        for (int bit = 0; bit < 32; ++bit) {
            float xv = xp[(size_t)bit * NIN];   // lanes = consecutive i -> coalesced
            word |= (xv != 0.0f) ? (1u << bit) : 0u;
        }
        uint32_t* colp = xbits + ((size_t)b * NIN + i) * NWORDS;
        colp[2 + w] = word;
        if (w == 0) { colp[0] = 0u; colp[1] = 0u; }      // guard words
    } else if (blk < 576) {
        int idx = (blk - 512) * 256 + tid;    // 16384 = g*1024 + h
        int g = idx >> 10, h = idx & 1023;
        const float* Wp = W    + (size_t)h * NIN + 8 * g;
        const float* Rp = draw + (size_t)h * NIN + 8 * g;
        uint32_t d0 = 0, d1 = 0, wq = 0;
        const int ordm[8] = {0, 4, 1, 5, 2, 6, 3, 7};
        #pragma unroll
        for (int j = 0; j < 4; ++j) {
            d0 |= (uint32_t)(int)rintf(50.0f / (1.0f + expf(-Rp[j])))     << (8 * j);
            d1 |= (uint32_t)(int)rintf(50.0f / (1.0f + expf(-Rp[4 + j]))) << (8 * j);
        }
        #pragma unroll
        for (int m = 0; m < 8; ++m) {
            int q = (int)rintf(fminf(fmaxf(Wp[ordm[m]] * WSCALE, -8.0f), 7.0f));
            wq |= ((uint32_t)q & 0xFu) << (4 * m);
        }
        dq2[(size_t)g * NHID + h] = make_uint2(d0, d1);
        wq8[(size_t)g * NHID + h] = wq;
    } else {
        int idx = (blk - 576) * 256 + tid;    // 1280 outputs
        if (idx < B_DIM * KSLOT) out[idx] = b_ro[0];
        else if (idx < B_DIM * KSLOT + T_DIM) out[idx] = 0.0f;
    }
}

// ---------------- fused sdot8 nibble-ladder + wave-relay LIF ----------------
// block = (b, hg of 64 h), 512 threads = 8 waves, grid 512 -> 2 blocks/CU (4 waves/SIMD).
// Round-7 lesson: 16 waves @ 64-VGPR cap spilled acc[] to scratch (WRITE_SIZE 19.6 MB,
// VALUBusy fell to 66%) — 8 waves @ 128 VGPR is the no-spill sweet spot (R6-measured).
__global__ __launch_bounds__(512, 4) void fused_kernel(
    const uint2* __restrict__ dq2, const uint32_t* __restrict__ wq8,
    const uint32_t* __restrict__ xbits, float* __restrict__ out,
    const float* __restrict__ w_ro, const int* __restrict__ ss, const int* __restrict__ se) {
    __shared__ uint32_t lds_x[NIN * NWORDS];  // [i][w]   17 KB
    __shared__ uint2    lds_d2[NG * 64];      // [g][hl]   8 KB (8 x u8 delays)
    __shared__ uint32_t lds_w[NG * 64];       // [g][hl]   4 KB (8 x i4 weights)
    __shared__ float st_v[64];
    __shared__ float st_rf[64];
    __shared__ float st_sacc[KSLOT][64];      // authoritative (lazy relay: fast path never touches)
    __shared__ int   flag;

    int bx = blockIdx.x;
    int hg = bx & 15;
    int b  = bx >> 4;
    int tid  = threadIdx.x;
    int lane = tid & 63;
    int sub  = tid >> 6;
    int hbase = hg * 64;

    for (int idx = tid; idx < NIN * NWORDS; idx += 512)
        lds_x[idx] = xbits[(size_t)b * NIN * NWORDS + idx];
    for (int idx = tid; idx < NG * 64; idx += 512) {
        int g = idx >> 6, hl = idx & 63;
        lds_d2[idx] = dq2[(size_t)g * NHID + hbase + hl];
        lds_w[idx]  = wq8[(size_t)g * NHID + hbase + hl];
    }
    if (tid < 64) { st_v[tid] = 0.0f; st_rf[tid] = 0.0f; }
    if (tid < KSLOT * 64) ((float*)st_sacc)[tid] = 0.0f;
    if (tid == 0) flag = 0;
    __syncthreads();

    int st_[KSLOT], en_[KSLOT];
    #pragma unroll
    for (int k = 0; k < KSLOT; ++k) {
        st_[k] = __builtin_amdgcn_readfirstlane(ss[k]);
        en_[k] = __builtin_amdgcn_readfirstlane(se[k]);
    }

    for (int rl = 0; rl < ROUNDS; ++rl) {
        int c  = __builtin_amdgcn_readfirstlane(rl * WAVES + sub);
        int t0 = c * 32;
        int acc[32];
        #pragma unroll
        for (int k = 0; k < 32; ++k) acc[k] = 0;
        #pragma unroll 2
        for (int g = 0; g < NG; ++g) {
            uint2 dd    = lds_d2[(g << 6) | lane];
            uint32_t wq = lds_w[(g << 6) | lane];
            uint32_t P0, P1, P2, P3, X[8];
            {   // streams 8g..8g+3: windows (bit k = spike at t0+k, delay folded)
                uint32_t win[4];
                #pragma unroll
                for (int j = 0; j < 4; ++j) {
                    int d  = (int)((dd.x >> (8 * j)) & 0xFFu);
                    int sp = 63 - d;                          // in [13,63]
                    int wbase = (8 * g + j) * NWORDS + c + (sp >> 5);
                    win[j] = funnel32(lds_x[wbase + 1], lds_x[wbase], (uint32_t)sp);
                }
                uint32_t A  = permb(win[1], win[0], 0x05010400u);
                uint32_t Bv = permb(win[1], win[0], 0x07030602u);
                uint32_t Cv = permb(win[3], win[2], 0x05010400u);
                uint32_t Dv = permb(win[3], win[2], 0x07030602u);
                P0 = permb(Cv, A,  0x05040100u);   // byte j = stream j, byte 0
                P1 = permb(Cv, A,  0x07060302u);
                P2 = permb(Dv, Bv, 0x05040100u);
                P3 = permb(Dv, Bv, 0x07060302u);
            }
            {   // streams 8g+4..8g+7, then nibble-interleave via bfi pattern
                uint32_t win[4];
                #pragma unroll
                for (int j = 0; j < 4; ++j) {
                    int d  = (int)((dd.y >> (8 * j)) & 0xFFu);
                    int sp = 63 - d;
                    int wbase = (8 * g + 4 + j) * NWORDS + c + (sp >> 5);
                    win[j] = funnel32(lds_x[wbase + 1], lds_x[wbase], (uint32_t)sp);
                }
                uint32_t A  = permb(win[1], win[0], 0x05010400u);
                uint32_t Bv = permb(win[1], win[0], 0x07030602u);
                uint32_t Cv = permb(win[3], win[2], 0x05010400u);
                uint32_t Dv = permb(win[3], win[2], 0x07030602u);
                uint32_t Q0 = permb(Cv, A,  0x05040100u);
                uint32_t Q1 = permb(Cv, A,  0x07060302u);
                uint32_t Q2 = permb(Dv, Bv, 0x05040100u);
                uint32_t Q3 = permb(Dv, Bv, 0x07060302u);
                // nibble order [0,4,1,5,2,6,3,7] matches wq8 packing
                X[0] = (P0 & 0x0F0F0F0Fu) | ((Q0 << 4) & 0xF0F0F0F0u);   // v_bfi_b32
                X[1] = ((P0 >> 4) & 0x0F0F0F0Fu) | (Q0 & 0xF0F0F0F0u);
                X[2] = (P1 & 0x0F0F0F0Fu) | ((Q1 << 4) & 0xF0F0F0F0u);
                X[3] = ((P1 >> 4) & 0x0F0F0F0Fu) | (Q1 & 0xF0F0F0F0u);
                X[4] = (P2 & 0x0F0F0F0Fu) | ((Q2 << 4) & 0xF0F0F0F0u);
                X[5] = ((P2 >> 4) & 0x0F0F0F0Fu) | (Q2 & 0xF0F0F0F0u);
                X[6] = (P3 & 0x0F0F0F0Fu) | ((Q3 << 4) & 0xF0F0F0F0u);
                X[7] = ((P3 >> 4) & 0x0F0F0F0Fu) | (Q3 & 0xF0F0F0F0u);
            }
            // X[gp] bit (4m+kk) = stream order[m] spike at t0 + 4*gp + kk
            #pragma unroll
            for (int gp = 0; gp < 8; ++gp) {
                acc[4 * gp]     = dot8acc(X[gp] & 0x11111111u,        wq, acc[4 * gp]);
                acc[4 * gp + 1] = dot8acc((X[gp] >> 1) & 0x11111111u, wq, acc[4 * gp + 1]);
                acc[4 * gp + 2] = dot8acc((X[gp] >> 2) & 0x11111111u, wq, acc[4 * gp + 2]);
                acc[4 * gp + 3] = dot8acc((X[gp] >> 3) & 0x11111111u, wq, acc[4 * gp + 3]);
            }
        }
        // ---- relay: wait for token ----
        while (__builtin_amdgcn_readfirstlane(*(volatile int*)&flag) != c)
            __builtin_amdgcn_s_sleep(1);
        float v  = st_v[lane];
        float rf = st_rf[lane];
        // ---- LIF fast path: assume no spike & rf<=0; trajectories are identical up to
        //      the first spike, so (rf>0 || max vn >= 1) exactly detects slow-path need.
        float vf = v, vmax = -1.0f;
        #pragma unroll
        for (int k = 0; k < 32; ++k) {
            float I = (float)acc[k] * (1.0f / WSCALE);
            vf = vf + 0.1f * (I - vf);            // same fp ops as slow path's active branch
            vmax = fmaxf(vmax, vf);
        }
        bool slow = (rf > 0.0f) || (vmax >= 1.0f);
        if (__ballot(slow) != 0ULL) {
            // ---- exact path (rare: >=7 sigma margin). sacc from authoritative LDS copy.
            float sacc[KSLOT];
            #pragma unroll
            for (int k = 0; k < KSLOT; ++k) sacc[k] = st_sacc[k][lane];
            #pragma unroll
            for (int k = 0; k < 32; ++k) {
                float I = (float)acc[k] * (1.0f / WSCALE);
                int t = t0 + k;
                bool active = (rf <= 0.0f);
                float vupd = v + 0.1f * (I - v);
                float vn = active ? vupd : v;
                bool spike = active && (vn >= 1.0f);
                unsigned long long bal = __ballot(spike);
                if (bal != 0ULL) {
                    if (spike) {
                        vn = 0.0f;                // V_RESET
                        #pragma unroll
                        for (int k2 = 0; k2 < KSLOT; ++k2)
                            if (t >= st_[k2] && t < en_[k2]) sacc[k2] += 1.0f;
                    }
                    rf = spike ? 2.0f : fmaxf(rf - 1.0f, 0.0f);
                    if (lane == 0) atomicAdd(&out[B_DIM * KSLOT + t], (float)__popcll(bal));
                } else {
                    rf = fmaxf(rf - 1.0f, 0.0f);
                }
                v = vn;
            }
            #pragma unroll
            for (int k = 0; k < KSLOT; ++k) st_sacc[k][lane] = sacc[k];
        } else {
            v = vf;                                // rf stays 0 (was <=0, decays to 0)
            rf = 0.0f;
        }
        st_v[lane]  = v;
        st_rf[lane] = rf;
        __threadfence_block();                     // drain LDS writes before flag release
        if (lane == 0) *(volatile int*)&flag = c + 1;
    }
    // ---- epilogue: after chunk 31's relay write, LDS sacc is final ----
    if (sub == WAVES - 1) {
        float wr = w_ro[hbase + lane];
        #pragma unroll
        for (int k = 0; k < KSLOT; ++k) {
            float val = st_sacc[k][lane] * wr;
            #pragma unroll
            for (int o = 32; o > 0; o >>= 1) val += __shfl_down(val, o);
            if (lane == 0) atomicAdd(&out[b * KSLOT + k], val);
        }
    }
}

extern "C" void kernel_launch(void* const* d_in, const int* in_sizes, int n_in,
                              void* d_out, int out_size, void* d_ws, size_t ws_size,
                              hipStream_t stream) {
    const float* x   = (const float*)d_in[0];
    const float* W   = (const float*)d_in[1];
    const float* drw = (const float*)d_in[2];
    const float* wro = (const float*)d_in[3];
    const float* bro = (const float*)d_in[4];
    const int*   ss  = (const int*)d_in[5];
    const int*   se  = (const int*)d_in[6];
    float* out = (float*)d_out;

    uintptr_t base = (uintptr_t)d_ws;
    size_t off = 0;
    auto take = [&](size_t bytes) {
        size_t o = off;
        off = (off + bytes + 255) & ~(size_t)255;
        return (void*)(base + o);
    };
    uint32_t* xbits = (uint32_t*)take((size_t)B_DIM * NIN * NWORDS * 4);
    uint2*    dq2   = (uint2*)take((size_t)NG * NHID * 8);
    uint32_t* wq8   = (uint32_t*)take((size_t)NG * NHID * 4);
    (void)ws_size;

    prep_kernel<<<581, 256, 0, stream>>>(x, W, drw, bro, xbits, dq2, wq8, out);
    fused_kernel<<<512, 512, 0, stream>>>(dq2, wq8, xbits, out, wro, ss, se);
}